// Round 4
// baseline (717.882 us; speedup 1.0000x reference)
//
#include <hip/hip_runtime.h>
#include <hip/hip_bf16.h>
#include <math.h>

#define Ntok 8192
#define Dm   1024
#define Hm   2048
#define NE   8

typedef __hip_bfloat16 bf16;
typedef __attribute__((ext_vector_type(8))) short short8;
typedef __attribute__((ext_vector_type(4))) float f32x4;

static __device__ __forceinline__ float b2f(bf16 v){ return __bfloat162float(v); }
static __device__ __forceinline__ bf16  f2b(float v){ return __float2bfloat16(v); }

// async global->LDS, 16B per lane; LDS dest is wave-uniform base (lane i lands at base + i*16)
static __device__ __forceinline__ void gl2lds16(const bf16* g, bf16* l) {
    __builtin_amdgcn_global_load_lds(
        (const __attribute__((address_space(1))) unsigned*)(const void*)g,
        (__attribute__((address_space(3))) unsigned*)(void*)l, 16, 0, 0);
}

// ---------------- dtype detect ----------------
__global__ void detect_kernel(const unsigned* __restrict__ xw, int* dtf)
{
    unsigned w = xw[threadIdx.x];
    int ex = (w >> 23) & 0xff;
    unsigned long long m = __ballot(ex < 200);
    if (threadIdx.x == 0) *dtf = (__popcll(m) > 32) ? 1 : 0;
}

// ---------------- gate: softmax + top-2 routing + fused x->bf16 conversion ----------------
__global__ __launch_bounds__(1024) void gate_kernel(
    const void* __restrict__ xv, const void* __restrict__ wgv,
    const int* __restrict__ dtf,
    int* cnt, float* Psum, float* wts, int* idx_buf, bf16* __restrict__ xb)
{
    int fp32 = *dtf;
    int tid  = threadIdx.x;
    int lane = tid & 63;
    int wv   = tid >> 6;                 // 0..15
    int n    = blockIdx.x * 16 + wv;

    __shared__ float lP[8];
    __shared__ int   lc[8];
    __shared__ int   gbase[8];
    __shared__ int   tslot[16][2];
    __shared__ int   texp[16][2];

    if (tid < 8) { lP[tid] = 0.f; lc[tid] = 0; }
    __syncthreads();

    float acc[NE];
    #pragma unroll
    for (int e = 0; e < NE; e++) acc[e] = 0.f;

    if (fp32) {
        const float* xr = (const float*)xv + (size_t)n * Dm;
        const float* Wg = (const float*)wgv;
        #pragma unroll
        for (int i = 0; i < 16; i++) {
            float xval = xr[lane + 64*i];
            xb[(size_t)n * Dm + lane + 64*i] = f2b(xval);
            #pragma unroll
            for (int e = 0; e < NE; e++) acc[e] += xval * Wg[e*Dm + lane + 64*i];
        }
    } else {
        const bf16* xr = (const bf16*)xv + (size_t)n * Dm;
        const bf16* Wg = (const bf16*)wgv;
        #pragma unroll
        for (int i = 0; i < 16; i++) {
            bf16 xraw = xr[lane + 64*i];
            xb[(size_t)n * Dm + lane + 64*i] = xraw;
            float xval = b2f(xraw);
            #pragma unroll
            for (int e = 0; e < NE; e++) acc[e] += xval * b2f(Wg[e*Dm + lane + 64*i]);
        }
    }
    #pragma unroll
    for (int e = 0; e < NE; e++) {
        float v = acc[e];
        #pragma unroll
        for (int off = 32; off > 0; off >>= 1) v += __shfl_xor(v, off);
        acc[e] = v;
    }
    float mx = acc[0];
    #pragma unroll
    for (int e = 1; e < NE; e++) mx = fmaxf(mx, acc[e]);
    float p[NE]; float s = 0.f;
    #pragma unroll
    for (int e = 0; e < NE; e++) { p[e] = expf(acc[e] - mx); s += p[e]; }
    float inv = 1.f / s;
    #pragma unroll
    for (int e = 0; e < NE; e++) p[e] *= inv;
    int e0 = 0;
    #pragma unroll
    for (int e = 1; e < NE; e++) if (p[e] > p[e0]) e0 = e;
    int e1 = (e0 == 0) ? 1 : 0;
    #pragma unroll
    for (int e = 0; e < NE; e++) if (e != e0 && p[e] > p[e1]) e1 = e;

    if (lane < NE) atomicAdd(&lP[lane], p[lane]);   // LDS atomic
    if (lane == 0) {
        tslot[wv][0] = atomicAdd(&lc[e0], 1);       // LDS atomic, local slot
        tslot[wv][1] = atomicAdd(&lc[e1], 1);
        texp[wv][0] = e0; texp[wv][1] = e1;
        wts[2*n]   = p[e0];
        wts[2*n+1] = p[e1];
    }
    __syncthreads();
    if (tid < 8) {
        gbase[tid] = atomicAdd(cnt + tid, lc[tid]);           // 8 global atomics/block
        atomicAdd(Psum + tid*16, lP[tid]);                    // 64B-strided
    }
    __syncthreads();
    if (lane == 0) {
        int ea = texp[wv][0], eb = texp[wv][1];
        idx_buf[ea*Ntok + gbase[ea] + tslot[wv][0]] = n;              // k=0
        idx_buf[eb*Ntok + gbase[eb] + tslot[wv][1]] = n | 0x10000;    // k=1 flag bit16
    }
}

// ---------------- aux loss + per-expert dense-slot offsets ----------------
__global__ void aux_kernel(const int* __restrict__ cnt, const float* __restrict__ Psum,
                           const int* __restrict__ dtf, int* __restrict__ offs,
                           void* __restrict__ out)
{
    if (threadIdx.x == 0) {
        float s = 0.f; int a = 0;
        for (int e = 0; e < NE; e++) {
            offs[e] = a; a += cnt[e];
            s += (float)cnt[e] * Psum[e*16];
        }
        float aux = 0.08f * s / (16384.f * 8192.f);
        if (*dtf) ((float*)out)[(size_t)Ntok * Dm] = aux;
        else      ((bf16*)out)[(size_t)Ntok * Dm] = f2b(aux);
    }
}

// ---------------- transpose (two sources, same shape): src[R][C] -> dst[C][R] bf16, 64x64 tiles ----------------
__global__ void transpose2_kernel(const void* __restrict__ sA, const void* __restrict__ sB,
                                  bf16* __restrict__ dA, bf16* __restrict__ dB,
                                  int R, int C, const int* __restrict__ dtf)
{
    __shared__ bf16 t[64][68];
    int mat = blockIdx.z >> 3, e = blockIdx.z & 7;
    const void* src = mat ? sB : sA;
    bf16* dst = mat ? dB : dA;
    size_t base = (size_t)e * R * C;
    int c0 = blockIdx.x * 64, r0 = blockIdx.y * 64;
    int tid = threadIdx.x;
    int lr = tid >> 4;            // 0..15
    int lc = (tid & 15) * 4;      // 0..60

    if (*dtf) {
        const float* s = (const float*)src + base;
        #pragma unroll
        for (int i = 0; i < 4; i++) {
            float4 v = *(const float4*)(s + (size_t)(r0 + lr + 16*i) * C + c0 + lc);
            t[lr+16*i][lc+0] = f2b(v.x); t[lr+16*i][lc+1] = f2b(v.y);
            t[lr+16*i][lc+2] = f2b(v.z); t[lr+16*i][lc+3] = f2b(v.w);
        }
    } else {
        const bf16* s = (const bf16*)src + base;
        #pragma unroll
        for (int i = 0; i < 4; i++) {
            bf16 v[4];
            *(uint2*)v = *(const uint2*)(s + (size_t)(r0 + lr + 16*i) * C + c0 + lc);
            t[lr+16*i][lc+0] = v[0]; t[lr+16*i][lc+1] = v[1];
            t[lr+16*i][lc+2] = v[2]; t[lr+16*i][lc+3] = v[3];
        }
    }
    __syncthreads();
    int oc = tid >> 2;            // 0..63
    int os = tid & 3;             // 16-element segment
    bf16 ov[16];
    #pragma unroll
    for (int j = 0; j < 16; j++) ov[j] = t[os*16 + j][oc];
    bf16* dp = dst + base + (size_t)(c0 + oc) * R + r0 + os*16;
    *(uint4*)dp       = *(uint4*)ov;
    *(uint4*)(dp + 8) = *(uint4*)(ov + 8);
}

// =====================================================================================
// Flat-phase single-buffered FFN GEMM (m97 mechanism: multi-block drain hiding).
// Tile: 256 A-rows x (MODE0: 64 h-cols dual-matrix | MODE1: 128 d-cols), BK=64.
// 512 threads (8 waves, 2Mx4N), per-wave 128 rows x 32 B-rows, acc[8][2] (64 AGPR).
// LDS 49 KiB -> 2-3 blocks/CU. Per K-tile: 6 gl2lds; VMW0; BAR; 20 ds_read + 32 MFMA
// (compiler-interleaved); BAR. 2 barriers per 32 MFMA (4x better than R3).
// Read swizzle: chunk ^= (row&7); inverse pre-applied to global source chunk.
// LDS slots (bf16 idx): A0 @0 (128x64), A1 @8192, B0 @16384 (64x64), B1 @20480.
// =====================================================================================

#define BAR()  { asm volatile("" ::: "memory"); __builtin_amdgcn_s_barrier(); asm volatile("" ::: "memory"); }
#define VMW0() asm volatile("s_waitcnt vmcnt(0)" ::: "memory")

#define LOADA(_mh) do { \
    int _ab = (_mh)*8192 + (wr*64 + mrow)*64; \
    _Pragma("unroll") \
    for (int _m = 0; _m < 4; _m++) { \
      _Pragma("unroll") \
      for (int _k = 0; _k < 2; _k++) \
        af[_m][_k] = *(const short8*)&smem[_ab + _m*1024 + kxo[_k]]; \
    } } while(0)

#define LOADBW() do { \
    int _bb = 16384 + (wc>>1)*4096 + ((wc&1)*32 + mrow)*64; \
    _Pragma("unroll") \
    for (int _n = 0; _n < 2; _n++) { \
      _Pragma("unroll") \
      for (int _k = 0; _k < 2; _k++) \
        bfr[_n][_k] = *(const short8*)&smem[_bb + _n*1024 + kxo[_k]]; \
    } } while(0)

#define MFMAQ(_mh) do { \
    _Pragma("unroll") \
    for (int _m = 0; _m < 4; _m++) \
      _Pragma("unroll") \
      for (int _n = 0; _n < 2; _n++) \
        _Pragma("unroll") \
        for (int _k = 0; _k < 2; _k++) \
          acc[(_mh)*4+_m][_n] = __builtin_amdgcn_mfma_f32_16x16x32_bf16( \
              af[_m][_k], bfr[_n][_k], acc[(_mh)*4+_m][_n], 0, 0, 0); \
    } while(0)

#define STAGE6() do { \
    gl2lds16(pA00, &smem[        w*512]); gl2lds16(pA01, &smem[ 4096 + w*512]); \
    gl2lds16(pA10, &smem[ 8192 + w*512]); gl2lds16(pA11, &smem[12288 + w*512]); \
    gl2lds16(pB00, &smem[16384 + w*512]); gl2lds16(pB01, &smem[20480 + w*512]); \
    pA00 += 64; pA01 += 64; pA10 += 64; pA11 += 64; pB00 += 64; pB01 += 64; } while(0)

template<int MODE>
__global__ __launch_bounds__(512, 4) void ffn_kernel(
    const bf16* __restrict__ Asrc,   // xb (MODE0) / hbuf (MODE1)
    const bf16* __restrict__ Bsrc1,  // w1t / w2t
    const bf16* __restrict__ Bsrc3,  // w3t / (unused)
    const void* __restrict__ bv1,    // b1 / b2
    const void* __restrict__ bv3,    // b3 / (unused)
    const int* __restrict__ dtf,
    const int* __restrict__ cnt, const int* __restrict__ offs,
    const int* __restrict__ idx_buf,
    bf16* __restrict__ Out)          // hbuf / outs
{
    const int KD = MODE ? Hm : Dm;
    const int NT = KD / 64;
    int e = blockIdx.z;
    int c = cnt[e];
    int m0 = blockIdx.y * 256;
    if (m0 >= c) return;
    int n0 = blockIdx.x * (MODE ? 128 : 64);
    int fp32 = *dtf;
    int slot0 = offs[e] + m0;

    __shared__ __align__(16) bf16 smem[24576];   // 48 KiB: A0,A1 (128x64), B0,B1 (64x64)
    __shared__ int tk[256];

    int tid = threadIdx.x;
    int cm = c - 1 - m0; if (cm > 255) cm = 255;
    if (tid < 256) {
        int r = tid > cm ? cm : tid;
        int v = idx_buf[e*Ntok + m0 + r];
        tk[tid] = MODE ? (2*(v & 0xffff) + (v >> 16)) : (v & 0xffff);
    }
    __syncthreads();

    int lane = tid & 63, w = tid >> 6;
    int wr = w >> 2, wc = w & 3;
    int mrow = lane & 15, kg = lane >> 4;
    int flip = mrow & 7;
    int kxo[2];
    kxo[0] = ((0*4 + kg) ^ flip) * 8;
    kxo[1] = ((1*4 + kg) ^ flip) * 8;

    // staging geometry: thread covers one row per 8KB issue; 16B chunk cs_src
    int rs = tid >> 3;                       // 0..63
    int cs_src = (tid & 7) ^ (rs & 7);       // inverse swizzle on global source

    const bf16 *pA00, *pA01, *pA10, *pA11, *pB00, *pB01;
    {
        int r00 = rs, r01 = 64 + rs, r10 = 128 + rs, r11 = 192 + rs;
        if (MODE == 0) {
            pA00 = Asrc + (size_t)tk[r00] * Dm + cs_src*8;
            pA01 = Asrc + (size_t)tk[r01] * Dm + cs_src*8;
            pA10 = Asrc + (size_t)tk[r10] * Dm + cs_src*8;
            pA11 = Asrc + (size_t)tk[r11] * Dm + cs_src*8;
        } else {
            int c00 = r00 > cm ? cm : r00, c01 = r01 > cm ? cm : r01;
            int c10 = r10 > cm ? cm : r10, c11 = r11 > cm ? cm : r11;
            pA00 = Asrc + (size_t)(slot0 + c00) * Hm + cs_src*8;
            pA01 = Asrc + (size_t)(slot0 + c01) * Hm + cs_src*8;
            pA10 = Asrc + (size_t)(slot0 + c10) * Hm + cs_src*8;
            pA11 = Asrc + (size_t)(slot0 + c11) * Hm + cs_src*8;
        }
        if (MODE == 0) {
            // B rows 0..127: mat=(r>>4)&1, hcol = n0 + ((r>>5)&3)*16 + (r&15)
            #pragma unroll
            for (int hl = 0; hl < 2; hl++) {
                int r = hl*64 + rs;
                int matb = (r >> 4) & 1;
                int hcol = n0 + ((r >> 5) & 3)*16 + (r & 15);
                const bf16* base = (matb ? Bsrc3 : Bsrc1) + (size_t)e*Hm*Dm
                                 + (size_t)hcol * Dm + cs_src*8;
                if (hl == 0) pB00 = base; else pB01 = base;
            }
        } else {
            pB00 = Bsrc1 + (size_t)e*Dm*Hm + (size_t)(n0 + rs     ) * Hm + cs_src*8;
            pB01 = Bsrc1 + (size_t)e*Dm*Hm + (size_t)(n0 + rs + 64) * Hm + cs_src*8;
        }
    }

    f32x4 acc[8][2];
    f32x4 z = {0.f, 0.f, 0.f, 0.f};
    #pragma unroll
    for (int m = 0; m < 8; m++) { acc[m][0] = z; acc[m][1] = z; }

    short8 af[4][2];
    short8 bfr[2][2];

    for (int t = 0; t < NT; ++t) {
        STAGE6();
        VMW0();
        BAR();
        LOADBW();
        LOADA(0);
        __builtin_amdgcn_s_setprio(1);
        MFMAQ(0);
        LOADA(1);
        MFMAQ(1);
        __builtin_amdgcn_s_setprio(0);
        __builtin_amdgcn_sched_barrier(0);
        BAR();
    }

    // ---- epilogue ----
    if (MODE == 0) {
        int hcol = n0 + wc*16 + mrow;
        float bb1 = fp32 ? ((const float*)bv1)[e*Hm + hcol] : b2f(((const bf16*)bv1)[e*Hm + hcol]);
        float bb3 = fp32 ? ((const float*)bv3)[e*Hm + hcol] : b2f(((const bf16*)bv3)[e*Hm + hcol]);
        #pragma unroll
        for (int ms = 0; ms < 8; ms++) {
            int rbase = (ms>>2)*128 + wr*64 + (ms&3)*16 + kg*4;
            #pragma unroll
            for (int j = 0; j < 4; j++) {
                int tr = rbase + j;
                if (m0 + tr < c) {
                    float v1 = acc[ms][0][j] + bb1;
                    float v3 = acc[ms][1][j] + bb3;
                    float hv = (v1 / (1.f + expf(-v1))) * v3;   // silu(v1)*v3
                    Out[(size_t)(slot0 + tr)*Hm + hcol] = f2b(hv);
                }
            }
        }
    } else {
        #pragma unroll
        for (int ns = 0; ns < 2; ns++) {
            int col = n0 + wc*32 + ns*16 + mrow;
            float bb2 = fp32 ? ((const float*)bv1)[e*Dm + col] : b2f(((const bf16*)bv1)[e*Dm + col]);
            #pragma unroll
            for (int ms = 0; ms < 8; ms++) {
                int rbase = (ms>>2)*128 + wr*64 + (ms&3)*16 + kg*4;
                #pragma unroll
                for (int j = 0; j < 4; j++) {
                    int tr = rbase + j;
                    if (m0 + tr < c)
                        Out[(size_t)tk[tr]*Dm + col] = f2b(acc[ms][ns][j] + bb2);
                }
            }
        }
    }
}

#undef LOADA
#undef LOADBW
#undef MFMAQ
#undef STAGE6

// ---------------- combine: y[n] = w0*out[2n] + w1*out[2n+1] ----------------
__global__ void combine_kernel(const bf16* __restrict__ outs, const float* __restrict__ wts,
                               const int* __restrict__ dtf, void* __restrict__ yv)
{
    int gid = blockIdx.x * 256 + threadIdx.x;
    int n = gid >> 7;
    int j = (gid & 127) * 8;
    float w0 = wts[2*n], w1 = wts[2*n+1];
    bf16 ra[8], rb[8];
    *(uint4*)ra = *(const uint4*)(outs + (size_t)(2*n)   * Dm + j);
    *(uint4*)rb = *(const uint4*)(outs + (size_t)(2*n+1) * Dm + j);
    float o[8];
    #pragma unroll
    for (int t = 0; t < 8; t++)
        o[t] = w0 * b2f(ra[t]) + w1 * b2f(rb[t]);
    if (*dtf) {
        float* y = (float*)yv + (size_t)n * Dm + j;
        *(float4*)y       = make_float4(o[0], o[1], o[2], o[3]);
        *(float4*)(y + 4) = make_float4(o[4], o[5], o[6], o[7]);
    } else {
        bf16 ro[8];
        #pragma unroll
        for (int t = 0; t < 8; t++) ro[t] = f2b(o[t]);
        *(uint4*)((bf16*)yv + (size_t)n * Dm + j) = *(uint4*)ro;
    }
}

extern "C" void kernel_launch(void* const* d_in, const int* in_sizes, int n_in,
                              void* d_out, int out_size, void* d_ws, size_t ws_size,
                              hipStream_t stream)
{
    (void)in_sizes; (void)n_in; (void)out_size; (void)ws_size;
    const void* x  = d_in[0];
    const void* Wg = d_in[1];
    const void* W1 = d_in[2];
    const void* b1 = d_in[3];
    const void* W2 = d_in[4];
    const void* b2 = d_in[5];
    const void* W3 = d_in[6];
    const void* b3 = d_in[7];

    char* ws = (char*)d_ws;
    int*   cnt  = (int*)ws;                      // [0,32)
    int*   dtf  = (int*)(ws + 64);               // dtype flag
    int*   offs = (int*)(ws + 512);              // [512,544)
    float* Psum = (float*)(ws + 1024);           // [1024,1536), stride 16 floats (64B/expert)
    float* wts  = (float*)(ws + 4096);           // 64 KB -> 69632
    int*   idx  = (int*)(ws + 69632);            // 256 KB -> 331776
    bf16* bufA  = (bf16*)(ws + 331776);          // 32 MiB (w1t, then w2t)
    bf16* bufB  = (bf16*)(ws + 33886208);        // 32 MiB (w3t, then outs)
    bf16* hbuf  = (bf16*)(ws + 67440640);        // 64 MiB
    bf16* outs  = bufB;
    bf16* xb    = (bf16*)d_out;                  // x as bf16 in d_out scratch (dead before combine)

    hipMemsetAsync(d_ws, 0, 4096, stream);
    detect_kernel<<<1, 64, 0, stream>>>((const unsigned*)x, dtf);
    // gate fuses x->bf16 conversion (writes xb) with routing
    gate_kernel<<<Ntok/16, 1024, 0, stream>>>(x, Wg, dtf, cnt, Psum, wts, idx, xb);
    aux_kernel<<<1, 64, 0, stream>>>(cnt, Psum, dtf, offs, d_out);
    // W1,W3: [D][H] -> [H][D]
    transpose2_kernel<<<dim3(Hm/64, Dm/64, 16), 256, 0, stream>>>(W1, W3, bufA, bufB, Dm, Hm, dtf);
    ffn_kernel<0><<<dim3(Hm/64, Ntok/256, NE), 512, 0, stream>>>(
        xb, bufA, bufB, b1, b3, dtf, cnt, offs, idx, hbuf);
    // W2: [H][D] -> [D][H]  (into bufA, w1t dead)
    transpose2_kernel<<<dim3(Dm/64, Hm/64, 8), 256, 0, stream>>>(W2, W2, bufA, bufA, Hm, Dm, dtf);
    ffn_kernel<1><<<dim3(Dm/128, Ntok/256, NE), 512, 0, stream>>>(
        hbuf, bufA, bufA, b2, b2, dtf, cnt, offs, idx, outs);
    combine_kernel<<<(Ntok*Dm/8)/256, 256, 0, stream>>>(outs, wts, dtf, d_out);
}